// Round 8
// baseline (2650.960 us; speedup 1.0000x reference)
//
#include <hip/hip_runtime.h>

// Dual-dtype boundary: inputs/outputs may be bf16 (u16 bits) or fp32; indices
// int32 or int64. A device-side sniffer decides per call. Internal state:
// fp32 masters (X, QX), bf16 for all GEMM-A-only intermediates (T1b, Xs, T2).
typedef unsigned short u16;
typedef __attribute__((ext_vector_type(8))) short bf16x8;
typedef __attribute__((ext_vector_type(4))) float f32x4;

__device__ __forceinline__ float b2f(u16 v) {
    return __uint_as_float(((unsigned)v) << 16);
}
__device__ __forceinline__ u16 f2b(float x) {
    unsigned u = __float_as_uint(x);
    unsigned r = u + 0x7FFFu + ((u >> 16) & 1u);   // round-to-nearest-even
    return (u16)(r >> 16);
}
__device__ __forceinline__ float4 load_bf4(const u16* p) {
    ushort4 q = *(const ushort4*)p;
    float4 f;
    f.x = b2f(q.x); f.y = b2f(q.y); f.z = b2f(q.z); f.w = b2f(q.w);
    return f;
}
__device__ __forceinline__ float4 in4(const void* p, long off, bool bf) {
    if (bf) return load_bf4((const u16*)p + off);
    return *(const float4*)((const float*)p + off);
}
__device__ __forceinline__ float in1(const void* p, long off, bool bf) {
    if (bf) return b2f(((const u16*)p)[off]);
    return ((const float*)p)[off];
}
__device__ __forceinline__ int inIdx(const void* p, long i, bool i64) {
    return ((const int*)p)[i64 ? 2 * i : i];
}

// ---------------- dtype sniffer ----------------
__global__ void sniff_kernel(const u16* __restrict__ x0bits, const int* __restrict__ arow,
                             int* __restrict__ flags) {
    if (threadIdx.x != 0 || blockIdx.x != 0) return;
    int plaus = 0;
    for (int i = 0; i < 256; ++i) {
        u16 v = x0bits[i];
        int e = (v >> 7) & 0xFF;
        if (v == 0 || (e >= 100 && e <= 135)) plaus++;
    }
    flags[0] = (plaus >= 200) ? 1 : 0;
    int nz = 0;
    for (int i = 1; i < 128; i += 2) nz += (arow[i] != 0);
    flags[1] = (nz == 0) ? 1 : 0;
}

// ---------------- trans: out[r][c] = v[r]*tw[c] + tb[c] ----------------
__global__ void trans_kernel(const void* __restrict__ v, const void* __restrict__ tw,
                             const void* __restrict__ tb, float* __restrict__ out,
                             int rows, const int* __restrict__ flags) {
    const bool bf = flags[0] != 0;
    int t = blockIdx.x * blockDim.x + threadIdx.x;
    int c4 = (t & 31) * 4;
    int r = t >> 5;
    if (r >= rows) return;
    float vv = in1(v, r, bf);
    float4 w4 = in4(tw, c4, bf);
    float4 b4 = in4(tb, c4, bf);
    float4 o;
    o.x = vv * w4.x + b4.x; o.y = vv * w4.y + b4.y;
    o.z = vv * w4.z + b4.z; o.w = vv * w4.w + b4.w;
    *(float4*)(out + (size_t)r * 128 + c4) = o;
}

// ---------------- weight prep: W[K x N] -> bf16 B-frag layout ----------------
__global__ void wprep_kernel(const void* __restrict__ src, u16* __restrict__ dst,
                             int K, int N, const int* __restrict__ flags) {
    const bool bf = flags[0] != 0;
    int idx = blockIdx.x * blockDim.x + threadIdx.x;
    if (idx >= K * N) return;
    int j = idx & 7, lane = (idx >> 3) & 63, t = idx >> 9;
    int KC = K >> 5;
    int kc = t % KC, ct = t / KC;
    int k = kc * 32 + (lane >> 4) * 8 + j;
    int nn = ct * 16 + (lane & 15);
    dst[idx] = f2b(in1(src, (long)k * N + nn, bf));
}

// ---------------- MFMA GEMM core (wave-tile body, shared by x-kernel & q-fused) ----
template<int KTOT, int NOUT, bool LEAKY, typename AT, typename CT>
__device__ __forceinline__ void gemm_tile(const AT* __restrict__ A, const u16* __restrict__ Wf,
                                          const void* __restrict__ bias, CT* __restrict__ C,
                                          int n, bool bf, int rbase, int lane) {
    constexpr int KC = KTOT / 32;
    constexpr int NT = NOUT / 16;
    const int quad = lane >> 4, col = lane & 15;
    int node = rbase + col; if (node >= n) node = n - 1;
    f32x4 acc[NT];
#pragma unroll
    for (int ct = 0; ct < NT; ++ct) acc[ct] = (f32x4){0.f, 0.f, 0.f, 0.f};
#pragma unroll
    for (int kc = 0; kc < KC; ++kc) {
        bf16x8 af;
        if constexpr (sizeof(AT) == 2) {
            af = *(const bf16x8*)((const u16*)A + (size_t)node * KTOT + kc * 32 + quad * 8);
        } else {
            const float* ap = (const float*)A + (size_t)node * KTOT + kc * 32 + quad * 8;
            float4 a0 = *(const float4*)ap;
            float4 a1 = *(const float4*)(ap + 4);
            af[0] = (short)f2b(a0.x); af[1] = (short)f2b(a0.y);
            af[2] = (short)f2b(a0.z); af[3] = (short)f2b(a0.w);
            af[4] = (short)f2b(a1.x); af[5] = (short)f2b(a1.y);
            af[6] = (short)f2b(a1.z); af[7] = (short)f2b(a1.w);
        }
#pragma unroll
        for (int ct = 0; ct < NT; ++ct) {
            bf16x8 wf = *(const bf16x8*)(Wf + (((size_t)ct * KC + kc) * 64 + lane) * 8);
            acc[ct] = __builtin_amdgcn_mfma_f32_16x16x32_bf16(af, wf, acc[ct], 0, 0, 0);
        }
    }
#pragma unroll
    for (int ct = 0; ct < NT; ++ct) {
        int colg = ct * 16 + col;
        float b = bias ? in1(bias, colg, bf) : 0.f;
#pragma unroll
        for (int r = 0; r < 4; ++r) {
            int row = rbase + quad * 4 + r;
            if (row >= n) continue;
            float v = acc[ct][r] + b;
            if (LEAKY) v = v > 0.f ? v : 0.01f * v;
            if constexpr (sizeof(CT) == 2) C[(size_t)row * NOUT + colg] = (CT)f2b(v);
            else                           C[(size_t)row * NOUT + colg] = (CT)v;
        }
    }
}

template<int KTOT, int NOUT, bool LEAKY, typename AT, typename CT>
__launch_bounds__(256)
__global__ void gemm_mfma_kernel(const AT* __restrict__ A, const u16* __restrict__ Wf,
                                 const void* __restrict__ bias, CT* __restrict__ C,
                                 int n, const int* __restrict__ flags) {
    const bool bf = flags[0] != 0;
    const int lane = threadIdx.x & 63;
    const int wave = threadIdx.x >> 6;
    const int rbase = (blockIdx.x * 4 + wave) * 16;
    if (rbase >= n) return;
    gemm_tile<KTOT, NOUT, LEAKY, AT, CT>(A, Wf, bias, C, n, bf, rbase, lane);
}

// ---------------- x-side CSR build ----------------
__global__ void zero_int_kernel(int* __restrict__ p, int n) {
    int i = blockIdx.x * blockDim.x + threadIdx.x;
    if (i < n) p[i] = 0;
}
__global__ void count_kernel(const void* __restrict__ rows, int e, int* __restrict__ cnt,
                             const int* __restrict__ flags) {
    const bool i64 = flags[1] != 0;
    int i = blockIdx.x * blockDim.x + threadIdx.x;
    if (i < e) atomicAdd(&cnt[inIdx(rows, i, i64)], 1);
}
__global__ void scanA_kernel(const int* __restrict__ cnt, int n, int* __restrict__ bsum) {
    int base = blockIdx.x * 2048;
    int s = 0;
    for (int j = threadIdx.x; j < 2048; j += 256) {
        int idx = base + j;
        if (idx < n) s += cnt[idx];
    }
#pragma unroll
    for (int off = 32; off; off >>= 1) s += __shfl_down(s, off);
    __shared__ int ws[4];
    if ((threadIdx.x & 63) == 0) ws[threadIdx.x >> 6] = s;
    __syncthreads();
    if (threadIdx.x == 0) bsum[blockIdx.x] = ws[0] + ws[1] + ws[2] + ws[3];
}
__global__ void scanB_kernel(int* __restrict__ bsum, int nb) {
    if (threadIdx.x == 0) {
        int acc = 0;
        for (int i = 0; i < nb; ++i) { int v = bsum[i]; bsum[i] = acc; acc += v; }
    }
}
__global__ void scanC_kernel(const int* __restrict__ cnt, int n, const int* __restrict__ bsum,
                             int* __restrict__ rowptr, int* __restrict__ cursor) {
    __shared__ int tsum[256];
    int base = blockIdx.x * 2048 + threadIdx.x * 8;
    int v[8]; int s = 0;
#pragma unroll
    for (int j = 0; j < 8; ++j) {
        int idx = base + j;
        v[j] = (idx < n) ? cnt[idx] : 0;
        s += v[j];
    }
    tsum[threadIdx.x] = s;
    __syncthreads();
    for (int off = 1; off < 256; off <<= 1) {
        int t = (threadIdx.x >= off) ? tsum[threadIdx.x - off] : 0;
        __syncthreads();
        tsum[threadIdx.x] += t;
        __syncthreads();
    }
    int excl = bsum[blockIdx.x] + tsum[threadIdx.x] - s;
#pragma unroll
    for (int j = 0; j < 8; ++j) {
        int idx = base + j;
        if (idx < n) { rowptr[idx] = excl; cursor[idx] = excl; }
        excl += v[j];
    }
}
// 4 edges per thread as independent atomic+store chains (MLP).
__global__ void scatter_kernel(const void* __restrict__ rows, const void* __restrict__ colsin,
                               const void* __restrict__ valsin, int e,
                               int* __restrict__ cursor, int2* __restrict__ csr_pack,
                               const int* __restrict__ flags) {
    const bool bf = flags[0] != 0;
    const bool i64 = flags[1] != 0;
    int base = blockIdx.x * 1024 + threadIdx.x;
#pragma unroll
    for (int k = 0; k < 4; ++k) {
        int i = base + k * 256;
        if (i < e) {
            int r = inIdx(rows, i, i64);
            int p = atomicAdd(&cursor[r], 1);
            int2 pk;
            pk.x = inIdx(colsin, i, i64);
            pk.y = __float_as_int(in1(valsin, i, bf));
            csr_pack[p] = pk;
        }
    }
}
// spmm: unroll x4 with 2 independent accumulator pairs for MLP.
__global__ void spmm_kernel(const u16* __restrict__ H, const int* __restrict__ rowptr,
                            const int* __restrict__ rowend, const int2* __restrict__ pack,
                            u16* __restrict__ out, int n) {
    int w = threadIdx.x >> 6;
    int lane = threadIdx.x & 63;
    int r = blockIdx.x * 4 + w;
    if (r >= n) return;
    int s = rowptr[r], e = rowend[r];
    float ax0 = 0.f, ay0 = 0.f, ax1 = 0.f, ay1 = 0.f;
    int i = s;
    for (; i + 3 < e; i += 4) {
        int2 p0 = pack[i], p1 = pack[i + 1], p2 = pack[i + 2], p3 = pack[i + 3];
        ushort2 h0 = *(const ushort2*)(H + (size_t)p0.x * 128 + lane * 2);
        ushort2 h1 = *(const ushort2*)(H + (size_t)p1.x * 128 + lane * 2);
        ushort2 h2 = *(const ushort2*)(H + (size_t)p2.x * 128 + lane * 2);
        ushort2 h3 = *(const ushort2*)(H + (size_t)p3.x * 128 + lane * 2);
        float v0 = __int_as_float(p0.y), v1 = __int_as_float(p1.y);
        float v2 = __int_as_float(p2.y), v3 = __int_as_float(p3.y);
        ax0 += v0 * b2f(h0.x) + v1 * b2f(h1.x);
        ay0 += v0 * b2f(h0.y) + v1 * b2f(h1.y);
        ax1 += v2 * b2f(h2.x) + v3 * b2f(h3.x);
        ay1 += v2 * b2f(h2.y) + v3 * b2f(h3.y);
    }
    for (; i < e; ++i) {
        int2 p0 = pack[i];
        float v0 = __int_as_float(p0.y);
        ushort2 h0 = *(const ushort2*)(H + (size_t)p0.x * 128 + lane * 2);
        ax0 += v0 * b2f(h0.x);
        ay0 += v0 * b2f(h0.y);
    }
    unsigned packed = (unsigned)f2b(ax0 + ax1) | ((unsigned)f2b(ay0 + ay1) << 16);
    *(unsigned*)(out + (size_t)r * 128 + lane * 2) = packed;
}

// ---------------- fused q-side step (single workgroup, 1024 threads) ----------------
// Phases: trans new rows -> qg GEMM -> CSR in LDS -> spmm (8-row chains) ->
// a1 -> a2 -> q/v GEMMs -> fragment prep. All q data is L2-resident.
__launch_bounds__(1024)
__global__ void qstep_kernel(float* __restrict__ QX, u16* __restrict__ QT1b,
                             u16* __restrict__ QXs, u16* __restrict__ QT2,
                             float* __restrict__ Qq, float* __restrict__ Qv,
                             int2* __restrict__ pack_q,
                             const void* __restrict__ qin,
                             const void* __restrict__ qrow, const void* __restrict__ qcol,
                             const void* __restrict__ qval,
                             const void* __restrict__ trans_w, const void* __restrict__ trans_b,
                             const u16* __restrict__ Wqg, const void* __restrict__ qg_b,
                             const u16* __restrict__ Wa1, const void* __restrict__ a1_b,
                             const u16* __restrict__ Wa2, const void* __restrict__ a2_b,
                             const u16* __restrict__ Wq, const u16* __restrict__ Wv,
                             u16* __restrict__ Qf, u16* __restrict__ Vf,
                             int m, int mprev, int qe, int mt32,
                             const int* __restrict__ flags) {
    __shared__ int cntL[1024];
    __shared__ int scanL[1024];
    __shared__ int rpL[408];
    __shared__ int curL[408];
    const bool bf  = flags[0] != 0;
    const bool i64 = flags[1] != 0;
    const int t = threadIdx.x;
    const int lane = t & 63, wv = t >> 6;

    // A: trans new rows (qin indexed from 0 -> rows mprev..m-1)
    for (int j = t; j < (m - mprev) * 32; j += 1024) {
        int r = j >> 5, c4 = (j & 31) * 4;
        float vvv = in1(qin, r, bf);
        float4 w4 = in4(trans_w, c4, bf);
        float4 b4 = in4(trans_b, c4, bf);
        float4 o;
        o.x = vvv * w4.x + b4.x; o.y = vvv * w4.y + b4.y;
        o.z = vvv * w4.z + b4.z; o.w = vvv * w4.w + b4.w;
        *(float4*)(QX + (size_t)(mprev + r) * 128 + c4) = o;
    }
    __syncthreads();
    // B: qg GEMM -> QT1b (bf16)
    for (int rbase = wv * 16; rbase < m; rbase += 256)
        gemm_tile<128, 128, false, float, u16>(QX, Wqg, qg_b, QT1b, m, bf, rbase, lane);
    __syncthreads();
    // C: CSR build in LDS
    for (int i = t; i < 1024; i += 1024) cntL[i] = 0;
    __syncthreads();
    for (int i = t; i < qe; i += 1024) atomicAdd(&cntL[inIdx(qrow, i, i64)], 1);
    __syncthreads();
    int myv = cntL[t];
    scanL[t] = myv;
    __syncthreads();
    for (int off = 1; off < 1024; off <<= 1) {
        int u = (t >= off) ? scanL[t - off] : 0;
        __syncthreads();
        scanL[t] += u;
        __syncthreads();
    }
    if (t < m) { rpL[t] = scanL[t] - myv; curL[t] = scanL[t] - myv; }
    __syncthreads();
    for (int i = t; i < qe; i += 1024) {
        int r = inIdx(qrow, i, i64);
        int p = atomicAdd(&curL[r], 1);
        int2 pk;
        pk.x = inIdx(qcol, i, i64);
        pk.y = __float_as_int(in1(qval, i, bf));
        pack_q[p] = pk;
    }
    __syncthreads();
    // D: spmm with 8 independent row chains per wave
    for (int g = wv * 8; g < m; g += 128) {
        float ax[8], ay[8];
        int ss[8], len[8];
        int mx = 0;
#pragma unroll
        for (int c = 0; c < 8; ++c) {
            int r = g + c;
            if (r < m) { ss[c] = rpL[r]; len[c] = curL[r] - rpL[r]; }
            else       { ss[c] = 0; len[c] = 0; }
            ax[c] = 0.f; ay[c] = 0.f;
            mx = max(mx, len[c]);
        }
        for (int it = 0; it < mx; ++it) {
#pragma unroll
            for (int c = 0; c < 8; ++c) {
                if (it < len[c]) {
                    int2 pk = pack_q[ss[c] + it];
                    ushort2 h = *(const ushort2*)(QT1b + (size_t)pk.x * 128 + lane * 2);
                    float v = __int_as_float(pk.y);
                    ax[c] += v * b2f(h.x);
                    ay[c] += v * b2f(h.y);
                }
            }
        }
#pragma unroll
        for (int c = 0; c < 8; ++c) {
            int r = g + c;
            if (r < m) {
                unsigned packed = (unsigned)f2b(ax[c]) | ((unsigned)f2b(ay[c]) << 16);
                *(unsigned*)(QXs + (size_t)r * 128 + lane * 2) = packed;
            }
        }
    }
    __syncthreads();
    // E: a1 GEMM (128->256, leaky) -> QT2
    for (int rbase = wv * 16; rbase < m; rbase += 256)
        gemm_tile<128, 256, true, u16, u16>(QXs, Wa1, a1_b, QT2, m, bf, rbase, lane);
    __syncthreads();
    // F: a2 GEMM (256->128) -> QX fp32
    for (int rbase = wv * 16; rbase < m; rbase += 256)
        gemm_tile<256, 128, false, u16, float>(QT2, Wa2, a2_b, QX, m, bf, rbase, lane);
    __syncthreads();
    // G: q,v GEMMs -> Qq, Qv fp32
    for (int rbase = wv * 16; rbase < m; rbase += 256) {
        gemm_tile<128, 128, false, float, float>(QX, Wq, nullptr, Qq, m, bf, rbase, lane);
        gemm_tile<128, 128, false, float, float>(QX, Wv, nullptr, Qv, m, bf, rbase, lane);
    }
    __syncthreads();
    // H: fragment prep (scale folded into Qf; padded queries -> 0)
    const int mt16 = mt32 * 2;
    const float scale = 0.17677669529663687f;
    for (int idx = t; idx < 4 * mt32 * 1024; idx += 1024) {
        {   // Q frag: B[k=dim=quad*8+j][n=query=lane&15]
            int j = idx & 7, ln = (idx >> 3) & 63;
            int tt = idx >> 9;
            int h = tt / mt16, qt = tt - h * mt16;
            int dim = ((ln >> 4) & 3) * 8 + j;
            int query = qt * 16 + (ln & 15);
            Qf[idx] = (query < m) ? f2b(Qq[(size_t)query * 128 + h * 32 + dim] * scale) : (u16)0;
        }
        {   // V frag: B[k=query=quad*8+j][n=dim=lane&15]
            int j = idx & 7, ln = (idx >> 3) & 63;
            int u = idx >> 9;
            int dh = u & 1, tt = u >> 1;
            int h = tt / mt32, qc = tt - h * mt32;
            int query = qc * 32 + ((ln >> 4) & 3) * 8 + j;
            int dim = dh * 16 + (ln & 15);
            Vf[idx] = (query < m) ? f2b(Qv[(size_t)query * 128 + h * 32 + dim]) : (u16)0;
        }
    }
}

// ---------------- MFMA cross-attention (x side) ----------------
__launch_bounds__(256)
__global__ void attn_mfma_kernel(const u16* __restrict__ Kb, const u16* __restrict__ Qf,
                                 const u16* __restrict__ Vf, float* __restrict__ X,
                                 int n, int m, int mt32, int pad) {
    __shared__ u16 Pbuf_all[4 * 16 * 40];
    const int h = blockIdx.y;
    const int wave = threadIdx.x >> 6;
    const int lane = threadIdx.x & 63;
    u16* Pbuf = Pbuf_all + wave * 16 * 40;
    const int nb = (blockIdx.x * 4 + wave) * 16;
    if (nb >= n) return;
    const int quad = lane >> 4, col = lane & 15;
    int node = nb + col; if (node >= n) node = n - 1;
    bf16x8 kf = *(const bf16x8*)(Kb + (size_t)node * 128 + h * 32 + quad * 8);
    f32x4 O0 = {0.f, 0.f, 0.f, 0.f}, O1 = {0.f, 0.f, 0.f, 0.f};
    const f32x4 zero = {0.f, 0.f, 0.f, 0.f};
    float Lp0 = 0.f, Lp1 = 0.f, Lp2 = 0.f, Lp3 = 0.f;
    const u16* Qbase = Qf + (size_t)h * (mt32 * 2) * 512;
    const u16* Vbase = Vf + (size_t)h * mt32 * 1024;
    for (int qc = 0; qc < mt32; ++qc) {
#pragma unroll
        for (int half = 0; half < 2; ++half) {
            bf16x8 qfr = *(const bf16x8*)(Qbase + (size_t)(qc * 2 + half) * 512 + lane * 8);
            f32x4 S = __builtin_amdgcn_mfma_f32_16x16x32_bf16(kf, qfr, zero, 0, 0, 0);
            float e0 = __expf(fminf(S[0], 80.f));
            float e1 = __expf(fminf(S[1], 80.f));
            float e2 = __expf(fminf(S[2], 80.f));
            float e3 = __expf(fminf(S[3], 80.f));
            Lp0 += e0; Lp1 += e1; Lp2 += e2; Lp3 += e3;
            int qoff = half * 16 + col;
            Pbuf[(quad * 4 + 0) * 40 + qoff] = f2b(e0);
            Pbuf[(quad * 4 + 1) * 40 + qoff] = f2b(e1);
            Pbuf[(quad * 4 + 2) * 40 + qoff] = f2b(e2);
            Pbuf[(quad * 4 + 3) * 40 + qoff] = f2b(e3);
        }
        bf16x8 pf = *(const bf16x8*)(Pbuf + col * 40 + quad * 8);
        bf16x8 v0 = *(const bf16x8*)(Vbase + (size_t)(qc * 2 + 0) * 512 + lane * 8);
        bf16x8 v1 = *(const bf16x8*)(Vbase + (size_t)(qc * 2 + 1) * 512 + lane * 8);
        O0 = __builtin_amdgcn_mfma_f32_16x16x32_bf16(pf, v0, O0, 0, 0, 0);
        O1 = __builtin_amdgcn_mfma_f32_16x16x32_bf16(pf, v1, O1, 0, 0, 0);
    }
#pragma unroll
    for (int mask = 1; mask < 16; mask <<= 1) {
        Lp0 += __shfl_xor(Lp0, mask, 64);
        Lp1 += __shfl_xor(Lp1, mask, 64);
        Lp2 += __shfl_xor(Lp2, mask, 64);
        Lp3 += __shfl_xor(Lp3, mask, 64);
    }
    float inv[4];
    inv[0] = 1.f / fmaxf(Lp0 - (float)pad, 1e-35f);
    inv[1] = 1.f / fmaxf(Lp1 - (float)pad, 1e-35f);
    inv[2] = 1.f / fmaxf(Lp2 - (float)pad, 1e-35f);
    inv[3] = 1.f / fmaxf(Lp3 - (float)pad, 1e-35f);
#pragma unroll
    for (int r = 0; r < 4; ++r) {
        int nd = nb + quad * 4 + r;
        if (nd < n) {
            float* xp = X + (size_t)nd * 128 + h * 32;
            xp[col]      += O0[r] * inv[r];
            xp[16 + col] += O1[r] * inv[r];
        }
    }
}

// ---------------- f32 -> output copy (bf16 or f32 per flag) ----------------
__global__ void out_writer_kernel(const float* __restrict__ in, void* __restrict__ out,
                                  long elem_off, int n4, const int* __restrict__ flags) {
    const bool bf = flags[0] != 0;
    int i = blockIdx.x * blockDim.x + threadIdx.x;
    if (i >= n4) return;
    float4 v = ((const float4*)in)[i];
    if (bf) {
        ushort4 q; q.x = f2b(v.x); q.y = f2b(v.y); q.z = f2b(v.z); q.w = f2b(v.w);
        ((ushort4*)((u16*)out + elem_off))[i] = q;
    } else {
        ((float4*)((float*)out + elem_off))[i] = v;
    }
}

extern "C" void kernel_launch(void* const* d_in, const int* in_sizes, int n_in,
                              void* d_out, int out_size, void* d_ws, size_t ws_size,
                              hipStream_t stream) {
    (void)n_in; (void)out_size; (void)ws_size;
    const void* trans_w = d_in[0];
    const void* trans_b = d_in[1];
    const void* g_w  = d_in[2];
    const void* g_b  = d_in[3];
    const void* qg_w = d_in[4];
    const void* qg_b = d_in[5];
    const void* q_w  = d_in[6];
    const void* k_w  = d_in[7];
    const void* v_w  = d_in[8];
    const void* a1_w = d_in[9];
    const void* a1_b = d_in[10];
    const void* a2_w = d_in[11];
    const void* a2_b = d_in[12];
    const void* x0   = d_in[13];
    const void* q0   = d_in[14];

    int ixin[3], iqin[3], iaval[3], iarow[3], iacol[3], iqval[3], iqrow[3], iqcol[3];
    if (in_sizes[16] == 100) {  // dict order
        for (int s = 0; s < 3; ++s) {
            ixin[s] = 15 + 2 * s; iqin[s] = 16 + 2 * s;
            int b = 21 + 6 * s;
            iaval[s] = b; iarow[s] = b + 1; iacol[s] = b + 2;
            iqval[s] = b + 3; iqrow[s] = b + 4; iqcol[s] = b + 5;
        }
    } else {                    // signature order
        int xs[3] = {15,16,17}, qs_[3] = {18,19,20};
        int av[3] = {21,22,23}, qv[3] = {24,25,26};
        int ar[3] = {27,29,31}, ac[3] = {28,30,32};
        int qr[3] = {33,35,37}, qc[3] = {34,36,38};
        for (int s = 0; s < 3; ++s) {
            ixin[s]=xs[s]; iqin[s]=qs_[s]; iaval[s]=av[s]; iqval[s]=qv[s];
            iarow[s]=ar[s]; iacol[s]=ac[s]; iqrow[s]=qr[s]; iqcol[s]=qc[s];
        }
    }

    // Workspace carve
    char* p = (char*)d_ws;
    auto alloc = [&](size_t bytes) -> char* {
        char* r = p;
        p += (bytes + 255) & ~(size_t)255;
        return r;
    };
    int*   flags = (int*)alloc(256);
    const int NMAX = 100000;
    float* X   = (float*)alloc((size_t)NMAX * 128 * 4);   // fp32 master (attn RMW)
    u16*   T1b = (u16*)  alloc((size_t)NMAX * 128 * 2);   // bf16: g-out / K
    u16*   Xs  = (u16*)  alloc((size_t)NMAX * 128 * 2);   // bf16 spmm out
    u16*   T2  = (u16*)  alloc((size_t)NMAX * 256 * 2);   // bf16 MLP hidden
    float* QX  = (float*)alloc((size_t)400 * 128 * 4);
    u16*   QT1b= (u16*)  alloc((size_t)400 * 128 * 2);
    u16*   QXs = (u16*)  alloc((size_t)400 * 128 * 2);
    u16*   QT2 = (u16*)  alloc((size_t)400 * 256 * 2);
    float* Qq  = (float*)alloc((size_t)400 * 128 * 4);
    float* Qv  = (float*)alloc((size_t)400 * 128 * 4);
    u16*   Qfrag = (u16*)alloc((size_t)4 * 13 * 1024 * 2);
    u16*   Vfrag = (u16*)alloc((size_t)4 * 13 * 1024 * 2);
    u16* Wg  = (u16*)alloc((size_t)128 * 128 * 2);
    u16* Wqg = (u16*)alloc((size_t)128 * 128 * 2);
    u16* Wa1 = (u16*)alloc((size_t)128 * 256 * 2);
    u16* Wa2 = (u16*)alloc((size_t)256 * 128 * 2);
    u16* Wk  = (u16*)alloc((size_t)128 * 128 * 2);
    u16* Wq  = (u16*)alloc((size_t)128 * 128 * 2);
    u16* Wv  = (u16*)alloc((size_t)128 * 128 * 2);
    int2*  csr_pack = (int2*)alloc((size_t)1600000 * 8);
    int2*  pack_q   = (int2*)alloc((size_t)6400 * 8);
    int*   cnt    = (int*)alloc((size_t)NMAX * 4);
    int*   rowptr = (int*)alloc((size_t)NMAX * 4);
    int*   cursor = (int*)alloc((size_t)NMAX * 4);
    int*   bsum   = (int*)alloc(256);

    sniff_kernel<<<1, 64, 0, stream>>>((const u16*)x0, (const int*)d_in[iarow[0]], flags);

    auto wprep = [&](const void* src, u16* dst, int K, int N) {
        wprep_kernel<<<(K * N + 255) / 256, 256, 0, stream>>>(src, dst, K, N, flags);
    };
    wprep(g_w,  Wg,  128, 128);
    wprep(qg_w, Wqg, 128, 128);
    wprep(a1_w, Wa1, 128, 256);
    wprep(a2_w, Wa2, 256, 128);
    wprep(k_w,  Wk,  128, 128);
    wprep(q_w,  Wq,  128, 128);
    wprep(v_w,  Wv,  128, 128);

    auto launch_trans = [&](const void* v, float* out, int rows) {
        trans_kernel<<<(rows * 32 + 255) / 256, 256, 0, stream>>>(v, trans_w, trans_b, out, rows, flags);
    };
    auto build_spmm_x = [&](const void* rows, const void* colsidx, const void* vals, int e,
                            int nrows, const u16* H, u16* OUT) {
        int nb = (nrows + 2047) / 2048;
        zero_int_kernel<<<(nrows + 255) / 256, 256, 0, stream>>>(cnt, nrows);
        count_kernel<<<(e + 255) / 256, 256, 0, stream>>>(rows, e, cnt, flags);
        scanA_kernel<<<nb, 256, 0, stream>>>(cnt, nrows, bsum);
        scanB_kernel<<<1, 64, 0, stream>>>(bsum, nb);
        scanC_kernel<<<nb, 256, 0, stream>>>(cnt, nrows, bsum, rowptr, cursor);
        scatter_kernel<<<(e + 1023) / 1024, 256, 0, stream>>>(rows, colsidx, vals, e,
                                                              cursor, csr_pack, flags);
        spmm_kernel<<<(nrows + 3) / 4, 256, 0, stream>>>(H, rowptr, cursor, csr_pack,
                                                         OUT, nrows);
    };

    int nprev = in_sizes[13];   // 25000
    int mprev = in_sizes[14];   // 100
    launch_trans(x0, X, nprev);
    launch_trans(q0, QX, mprev);

    const int ns[3] = {50000, 75000, 100000};
    const int ms[3] = {200, 300, 400};
    for (int s = 0; s < 3; ++s) {
        const int n = ns[s], m = ms[s];
        const int e  = in_sizes[iaval[s]];
        const int qe = in_sizes[iqval[s]];
        const int mt32 = (m + 31) / 32;
        const int pad = mt32 * 32 - m;
        launch_trans(d_in[ixin[s]], X + (size_t)nprev * 128, n - nprev);
        const int gb = (n + 63) / 64;
        // x = spmm(A, x@g_w + g_b)          (T1b bf16, Xs bf16)
        gemm_mfma_kernel<128, 128, false, float, u16><<<gb, 256, 0, stream>>>(X, Wg, g_b, T1b, n, flags);
        build_spmm_x(d_in[iarow[s]], d_in[iacol[s]], d_in[iaval[s]], e, n, T1b, Xs);
        // entire q chain fused (trans, qg, CSR, spmm, MLP, q/v, prep)
        qstep_kernel<<<1, 1024, 0, stream>>>(QX, QT1b, QXs, QT2, Qq, Qv, pack_q,
                                             d_in[iqin[s]], d_in[iqrow[s]], d_in[iqcol[s]],
                                             d_in[iqval[s]], trans_w, trans_b,
                                             Wqg, qg_b, Wa1, a1_b, Wa2, a2_b, Wq, Wv,
                                             Qfrag, Vfrag, m, mprev, qe, mt32, flags);
        // x-side MLP
        gemm_mfma_kernel<128, 256, true, u16, u16><<<gb, 256, 0, stream>>>(Xs, Wa1, a1_b, T2, n, flags);
        gemm_mfma_kernel<256, 128, false, u16, float><<<gb, 256, 0, stream>>>(T2, Wa2, a2_b, X, n, flags);
        // k = x@k_w (bf16), then attention updates X
        gemm_mfma_kernel<128, 128, false, float, u16><<<gb, 256, 0, stream>>>(X, Wk, nullptr, T1b, n, flags);
        attn_mfma_kernel<<<dim3((n + 63) / 64, 4), 256, 0, stream>>>(T1b, Qfrag, Vfrag, X, n, m, mt32, pad);
        nprev = n;
        mprev = m;
    }

    // outputs: x (100000x128) then qx (400x128)
    const int n4x = 100000 * 128 / 4;
    const int n4q = 400 * 128 / 4;
    out_writer_kernel<<<(n4x + 255) / 256, 256, 0, stream>>>(X, d_out, 0, n4x, flags);
    out_writer_kernel<<<(n4q + 255) / 256, 256, 0, stream>>>(QX, d_out, (long)100000 * 128, n4q, flags);
}